// Round 10
// baseline (123.020 us; speedup 1.0000x reference)
//
#include <hip/hip_runtime.h>
#include <hip/hip_cooperative_groups.h>
#include <float.h>

namespace cg = cooperative_groups;

#define B_TOK 256
#define N_OUT 512
#define K_IN  1024

#define KSPLIT 8
#define KC     (K_IN / KSPLIT)   // 128 k per block
#define BT     16                // b rows per block (4 per wave)
#define NT     64                // n per block (1 per lane)

// ---------------- Cooperative fused kernel ----------------
// Phase 1 == R5 stage1 verbatim (best measured interior): grid (16 bg, 8 ng,
// 8 kc) = 1024 blocks, 256 thr = 4 waves. w-tile [64n][128k] in swizzled LDS
// (1 conflict-free ds_read_b128 per 4k); x via wave-uniform scalar loads.
// Then grid.sync() (runtime-correct cross-XCD visibility), then R5 stage2
// inlined: 32768 float4 slots over 262144 threads.
__global__ __launch_bounds__(256)
void mam_coop(const float* __restrict__ x, const float* __restrict__ w,
              const float* __restrict__ bias, float* __restrict__ out,
              float* __restrict__ pmx, float* __restrict__ pmn) {
    __shared__ float ws[NT * KC];   // 32 KB

    const int tid = threadIdx.x;
    const int b0  = blockIdx.x * BT;
    const int n0  = blockIdx.y * NT;
    const int kc  = blockIdx.z * KC;

    // ---- stage w[n0..+63][kc..+127] -> LDS (swizzled 16B chunks) ----
    {
        const int r  = tid >> 2;
        const int cb = tid & 3;
        const float* gsrc = w + (size_t)(n0 + r) * K_IN + kc;
#pragma unroll
        for (int j = 0; j < 8; ++j) {
            const int c = cb + 4 * j;
            const float4 v = *reinterpret_cast<const float4*>(gsrc + c * 4);
            *reinterpret_cast<float4*>(&ws[r * KC + ((c ^ (r & 7)) << 2)]) = v;
        }
    }
    __syncthreads();

    // ---- compute: lane = one n; wave = 4 b rows; x wave-uniform -> s_load ----
    const int wv = __builtin_amdgcn_readfirstlane(tid >> 6);  // 0..3, SGPR
    const int ln = tid & 63;
    const float* xb0 = x + (size_t)(b0 + wv * 4 + 0) * K_IN + kc;
    const float* xb1 = x + (size_t)(b0 + wv * 4 + 1) * K_IN + kc;
    const float* xb2 = x + (size_t)(b0 + wv * 4 + 2) * K_IN + kc;
    const float* xb3 = x + (size_t)(b0 + wv * 4 + 3) * K_IN + kc;

    float mx0 = -FLT_MAX, mx1 = -FLT_MAX, mx2 = -FLT_MAX, mx3 = -FLT_MAX;
    float mn0 =  FLT_MAX, mn1 =  FLT_MAX, mn2 =  FLT_MAX, mn3 =  FLT_MAX;

    const int swz = ln & 7;
#pragma unroll 4
    for (int c = 0; c < KC / 4; ++c) {            // 32 iters of 4 k
        const float4 wk = *reinterpret_cast<const float4*>(
            &ws[ln * KC + ((c ^ swz) << 2)]);     // conflict-free b128
        const float4 x0 = *reinterpret_cast<const float4*>(xb0 + c * 4);
        const float4 x1 = *reinterpret_cast<const float4*>(xb1 + c * 4);
        const float4 x2 = *reinterpret_cast<const float4*>(xb2 + c * 4);
        const float4 x3 = *reinterpret_cast<const float4*>(xb3 + c * 4);

        {   const float p0 = x0.x * wk.x, p1 = x0.y * wk.y, p2 = x0.z * wk.z, p3 = x0.w * wk.w;
            mx0 = fmaxf(fmaxf(mx0, p0), p1); mx0 = fmaxf(fmaxf(mx0, p2), p3);
            mn0 = fminf(fminf(mn0, p0), p1); mn0 = fminf(fminf(mn0, p2), p3); }
        {   const float p0 = x1.x * wk.x, p1 = x1.y * wk.y, p2 = x1.z * wk.z, p3 = x1.w * wk.w;
            mx1 = fmaxf(fmaxf(mx1, p0), p1); mx1 = fmaxf(fmaxf(mx1, p2), p3);
            mn1 = fminf(fminf(mn1, p0), p1); mn1 = fminf(fminf(mn1, p2), p3); }
        {   const float p0 = x2.x * wk.x, p1 = x2.y * wk.y, p2 = x2.z * wk.z, p3 = x2.w * wk.w;
            mx2 = fmaxf(fmaxf(mx2, p0), p1); mx2 = fmaxf(fmaxf(mx2, p2), p3);
            mn2 = fminf(fminf(mn2, p0), p1); mn2 = fminf(fminf(mn2, p2), p3); }
        {   const float p0 = x3.x * wk.x, p1 = x3.y * wk.y, p2 = x3.z * wk.z, p3 = x3.w * wk.w;
            mx3 = fmaxf(fmaxf(mx3, p0), p1); mx3 = fmaxf(fmaxf(mx3, p2), p3);
            mn3 = fminf(fminf(mn3, p0), p1); mn3 = fminf(fminf(mn3, p2), p3); }
    }

    // ---- write this block's partial rows (coalesced 256B per row) ----
    const size_t plane = (size_t)B_TOK * N_OUT;
    const size_t base  = (size_t)blockIdx.z * plane
                       + (size_t)(b0 + wv * 4) * N_OUT + n0 + ln;
    pmx[base + 0 * N_OUT] = mx0;  pmn[base + 0 * N_OUT] = mn0;
    pmx[base + 1 * N_OUT] = mx1;  pmn[base + 1 * N_OUT] = mn1;
    pmx[base + 2 * N_OUT] = mx2;  pmn[base + 2 * N_OUT] = mn2;
    pmx[base + 3 * N_OUT] = mx3;  pmn[base + 3 * N_OUT] = mn3;

    // ---- device-wide barrier (runtime handles cross-XCD visibility) ----
    cg::this_grid().sync();

    // ---- phase 2: combine 8 planes + bias (R5 stage2 body) ----
    const int bid  = blockIdx.x + 16 * (blockIdx.y + 8 * blockIdx.z);  // 0..1023
    const int slot = bid * 256 + tid;                                  // 0..262143
    if (slot < (B_TOK * N_OUT) / 4) {
        const size_t i4 = (size_t)slot * 4;
        float4 MX = *reinterpret_cast<const float4*>(pmx + i4);
        float4 MN = *reinterpret_cast<const float4*>(pmn + i4);
#pragma unroll
        for (int p = 1; p < KSPLIT; ++p) {
            const float4 a = *reinterpret_cast<const float4*>(pmx + (size_t)p * plane + i4);
            const float4 d = *reinterpret_cast<const float4*>(pmn + (size_t)p * plane + i4);
            MX.x = fmaxf(MX.x, a.x); MX.y = fmaxf(MX.y, a.y);
            MX.z = fmaxf(MX.z, a.z); MX.w = fmaxf(MX.w, a.w);
            MN.x = fminf(MN.x, d.x); MN.y = fminf(MN.y, d.y);
            MN.z = fminf(MN.z, d.z); MN.w = fminf(MN.w, d.w);
        }
        const float4 bb = *reinterpret_cast<const float4*>(bias + (i4 & (N_OUT - 1)));
        float4 o;
        o.x = MX.x + MN.x + bb.x; o.y = MX.y + MN.y + bb.y;
        o.z = MX.z + MN.z + bb.z; o.w = MX.w + MN.w + bb.w;
        *reinterpret_cast<float4*>(out + i4) = o;
    }
}

// ---------------- Fallback 2-kernel path (R5, proven) ----------------
__global__ __launch_bounds__(256)
void mam_stage1(const float* __restrict__ x, const float* __restrict__ w,
                float* __restrict__ pmx, float* __restrict__ pmn) {
    __shared__ float ws[NT * KC];
    const int tid = threadIdx.x;
    const int b0  = blockIdx.x * BT;
    const int n0  = blockIdx.y * NT;
    const int kc  = blockIdx.z * KC;
    {
        const int r  = tid >> 2;
        const int cb = tid & 3;
        const float* gsrc = w + (size_t)(n0 + r) * K_IN + kc;
#pragma unroll
        for (int j = 0; j < 8; ++j) {
            const int c = cb + 4 * j;
            const float4 v = *reinterpret_cast<const float4*>(gsrc + c * 4);
            *reinterpret_cast<float4*>(&ws[r * KC + ((c ^ (r & 7)) << 2)]) = v;
        }
    }
    __syncthreads();
    const int wv = __builtin_amdgcn_readfirstlane(tid >> 6);
    const int ln = tid & 63;
    const float* xb0 = x + (size_t)(b0 + wv * 4 + 0) * K_IN + kc;
    const float* xb1 = x + (size_t)(b0 + wv * 4 + 1) * K_IN + kc;
    const float* xb2 = x + (size_t)(b0 + wv * 4 + 2) * K_IN + kc;
    const float* xb3 = x + (size_t)(b0 + wv * 4 + 3) * K_IN + kc;
    float mx0 = -FLT_MAX, mx1 = -FLT_MAX, mx2 = -FLT_MAX, mx3 = -FLT_MAX;
    float mn0 =  FLT_MAX, mn1 =  FLT_MAX, mn2 =  FLT_MAX, mn3 =  FLT_MAX;
    const int swz = ln & 7;
#pragma unroll 4
    for (int c = 0; c < KC / 4; ++c) {
        const float4 wk = *reinterpret_cast<const float4*>(&ws[ln * KC + ((c ^ swz) << 2)]);
        const float4 x0 = *reinterpret_cast<const float4*>(xb0 + c * 4);
        const float4 x1 = *reinterpret_cast<const float4*>(xb1 + c * 4);
        const float4 x2 = *reinterpret_cast<const float4*>(xb2 + c * 4);
        const float4 x3 = *reinterpret_cast<const float4*>(xb3 + c * 4);
        {   const float p0 = x0.x * wk.x, p1 = x0.y * wk.y, p2 = x0.z * wk.z, p3 = x0.w * wk.w;
            mx0 = fmaxf(fmaxf(mx0, p0), p1); mx0 = fmaxf(fmaxf(mx0, p2), p3);
            mn0 = fminf(fminf(mn0, p0), p1); mn0 = fminf(fminf(mn0, p2), p3); }
        {   const float p0 = x1.x * wk.x, p1 = x1.y * wk.y, p2 = x1.z * wk.z, p3 = x1.w * wk.w;
            mx1 = fmaxf(fmaxf(mx1, p0), p1); mx1 = fmaxf(fmaxf(mx1, p2), p3);
            mn1 = fminf(fminf(mn1, p0), p1); mn1 = fminf(fminf(mn1, p2), p3); }
        {   const float p0 = x2.x * wk.x, p1 = x2.y * wk.y, p2 = x2.z * wk.z, p3 = x2.w * wk.w;
            mx2 = fmaxf(fmaxf(mx2, p0), p1); mx2 = fmaxf(fmaxf(mx2, p2), p3);
            mn2 = fminf(fminf(mn2, p0), p1); mn2 = fminf(fminf(mn2, p2), p3); }
        {   const float p0 = x3.x * wk.x, p1 = x3.y * wk.y, p2 = x3.z * wk.z, p3 = x3.w * wk.w;
            mx3 = fmaxf(fmaxf(mx3, p0), p1); mx3 = fmaxf(fmaxf(mx3, p2), p3);
            mn3 = fminf(fminf(mn3, p0), p1); mn3 = fminf(fminf(mn3, p2), p3); }
    }
    const size_t plane = (size_t)B_TOK * N_OUT;
    const size_t base  = (size_t)blockIdx.z * plane
                       + (size_t)(b0 + wv * 4) * N_OUT + n0 + ln;
    pmx[base + 0 * N_OUT] = mx0;  pmn[base + 0 * N_OUT] = mn0;
    pmx[base + 1 * N_OUT] = mx1;  pmn[base + 1 * N_OUT] = mn1;
    pmx[base + 2 * N_OUT] = mx2;  pmn[base + 2 * N_OUT] = mn2;
    pmx[base + 3 * N_OUT] = mx3;  pmn[base + 3 * N_OUT] = mn3;
}

__global__ __launch_bounds__(256)
void mam_stage2(const float* __restrict__ pmx, const float* __restrict__ pmn,
                const float* __restrict__ bias, float* __restrict__ out) {
    const size_t i4 = ((size_t)blockIdx.x * 256 + threadIdx.x) * 4;
    const size_t plane = (size_t)B_TOK * N_OUT;
    float4 MX = *reinterpret_cast<const float4*>(pmx + i4);
    float4 MN = *reinterpret_cast<const float4*>(pmn + i4);
#pragma unroll
    for (int p = 1; p < KSPLIT; ++p) {
        const float4 a = *reinterpret_cast<const float4*>(pmx + (size_t)p * plane + i4);
        const float4 d = *reinterpret_cast<const float4*>(pmn + (size_t)p * plane + i4);
        MX.x = fmaxf(MX.x, a.x); MX.y = fmaxf(MX.y, a.y);
        MX.z = fmaxf(MX.z, a.z); MX.w = fmaxf(MX.w, a.w);
        MN.x = fminf(MN.x, d.x); MN.y = fminf(MN.y, d.y);
        MN.z = fminf(MN.z, d.z); MN.w = fminf(MN.w, d.w);
    }
    const float4 bb = *reinterpret_cast<const float4*>(bias + (i4 & (N_OUT - 1)));
    float4 o;
    o.x = MX.x + MN.x + bb.x; o.y = MX.y + MN.y + bb.y;
    o.z = MX.z + MN.z + bb.z; o.w = MX.w + MN.w + bb.w;
    *reinterpret_cast<float4*>(out + i4) = o;
}

__global__ __launch_bounds__(256)
void mam_simple(const float* __restrict__ x, const float* __restrict__ w,
                const float* __restrict__ bias, float* __restrict__ out) {
    const int idx = blockIdx.x * 256 + threadIdx.x;
    const int b = idx / N_OUT, n = idx % N_OUT;
    const float* xr = x + (size_t)b * K_IN;
    const float* wr = w + (size_t)n * K_IN;
    float mx = -FLT_MAX, mn = FLT_MAX;
#pragma unroll 4
    for (int k = 0; k < K_IN; k += 4) {
        const float4 xv = *reinterpret_cast<const float4*>(xr + k);
        const float4 wv = *reinterpret_cast<const float4*>(wr + k);
        const float p0 = xv.x * wv.x, p1 = xv.y * wv.y;
        const float p2 = xv.z * wv.z, p3 = xv.w * wv.w;
        mx = fmaxf(fmaxf(mx, p0), p1);
        mx = fmaxf(fmaxf(mx, p2), p3);
        mn = fminf(fminf(mn, p0), p1);
        mn = fminf(fminf(mn, p2), p3);
    }
    out[idx] = mx + mn + bias[n];
}

extern "C" void kernel_launch(void* const* d_in, const int* in_sizes, int n_in,
                              void* d_out, int out_size, void* d_ws, size_t ws_size,
                              hipStream_t stream) {
    const float* x    = (const float*)d_in[0];   // [256,1024]
    const float* w    = (const float*)d_in[1];   // [512,1024]
    const float* bias = (const float*)d_in[2];   // [512]
    float* out = (float*)d_out;                  // [256,512] f32

    const size_t plane = (size_t)B_TOK * N_OUT;
    const size_t need  = 2 * (size_t)KSPLIT * plane * sizeof(float);  // 8 MB

    if (ws_size >= need) {
        float* pmx = (float*)d_ws;
        float* pmn = pmx + (size_t)KSPLIT * plane;
        void* args[] = { (void*)&x, (void*)&w, (void*)&bias,
                         (void*)&out, (void*)&pmx, (void*)&pmn };
        hipError_t e = hipLaunchCooperativeKernel(
            reinterpret_cast<void*>(mam_coop),
            dim3(B_TOK / BT, N_OUT / NT, KSPLIT), dim3(256, 1, 1),
            args, 0, stream);
        if (e != hipSuccess) {
            // proven 2-kernel fallback
            mam_stage1<<<dim3(B_TOK / BT, N_OUT / NT, KSPLIT), 256, 0, stream>>>(x, w, pmx, pmn);
            mam_stage2<<<(int)(plane / 4 / 256), 256, 0, stream>>>(pmx, pmn, bias, out);
        }
    } else {
        mam_simple<<<(B_TOK * N_OUT) / 256, 256, 0, stream>>>(x, w, bias, out);
    }
}

// Round 11
// 29.898 us; speedup vs baseline: 4.1147x; 4.1147x over previous
//
#include <hip/hip_runtime.h>
#include <float.h>

#define B_TOK 256
#define N_OUT 512
#define K_IN  1024

#define BT   8     // b rows per block
#define NT   64    // n cols per block (lane = n)
#define CHK  128   // k per staged chunk
#define NCHK (K_IN / CHK)

// Single kernel, no workspace, no cross-block dependencies.
// Grid (32 bg, 8 ng) = 256 blocks = 1/CU. Block 512 thr = 8 waves:
// wid = ws*2 + wb : wb = b-half (4 rows), ws = k-sub (32 k of each 128-chunk).
// Per chunk: w[64n][128k] -> XOR-swizzled LDS (double-buffered, reg-staged,
// loads issued before compute / written after - T14); x read as wave-uniform
// float4 -> s_load_dwordx4 (scalar pipe, zero VMEM in loop).
// Inner 4k-iter: 1 conflict-free ds_read_b128 + 4 scalar x loads -> 16 products
// x 4 b-rows (32 VALU: 16 mul + 8 max3 + 8 min3).
// End: 8-wave (4 k-sub) reduce via 16KB LDS aliasing buf0, + bias, write out.
__global__ __launch_bounds__(512)
void mam_single(const float* __restrict__ x, const float* __restrict__ w,
                const float* __restrict__ bias, float* __restrict__ out) {
    __shared__ float buf[2][NT * CHK];   // 2 x 32 KB

    const int tid = threadIdx.x;
    const int b0  = blockIdx.x * BT;
    const int n0  = blockIdx.y * NT;

    const int wid = __builtin_amdgcn_readfirstlane(tid >> 6);  // 0..7, SGPR
    const int wb  = wid & 1;     // b half: rows 4*wb .. 4*wb+3
    const int ws  = wid >> 1;    // k sub-chunk: 32 k within each 128-chunk
    const int ln  = tid & 63;    // lane = n

    // staging map: s = tid + 512*i (i<4) -> row r = s>>5 (0..63), chunk c = s&31.
    // 32 consecutive lanes load one row's 512B: fully coalesced.
    const int sr = tid >> 5;     // 0..15, rows advance by 16
    const int sc = tid & 31;

    float mx0 = -FLT_MAX, mx1 = -FLT_MAX, mx2 = -FLT_MAX, mx3 = -FLT_MAX;
    float mn0 =  FLT_MAX, mn1 =  FLT_MAX, mn2 =  FLT_MAX, mn3 =  FLT_MAX;

    // ---- prologue: stage chunk 0 ----
    float4 st[4];
#pragma unroll
    for (int i = 0; i < 4; ++i) {
        const int r = sr + 16 * i;
        st[i] = *reinterpret_cast<const float4*>(w + (size_t)(n0 + r) * K_IN + 4 * sc);
    }
#pragma unroll
    for (int i = 0; i < 4; ++i) {
        const int r = sr + 16 * i;
        *reinterpret_cast<float4*>(&buf[0][r * CHK + ((sc ^ (r & 7)) << 2)]) = st[i];
    }

    const int swz = ln & 7;

    for (int cc = 0; cc < NCHK; ++cc) {
        __syncthreads();               // chunk cc staged; chunk cc-1 reads done
        const int cur = cc & 1;

        // issue next chunk's global loads early (hide HBM/L2 latency under compute)
        if (cc + 1 < NCHK) {
#pragma unroll
            for (int i = 0; i < 4; ++i) {
                const int r = sr + 16 * i;
                st[i] = *reinterpret_cast<const float4*>(
                    w + (size_t)(n0 + r) * K_IN + (cc + 1) * CHK + 4 * sc);
            }
        }

        // wave-uniform x pointers for this chunk's k-sub
        const float* xp  = x + (size_t)b0 * K_IN + cc * CHK + ws * 32;
        const float* xq0 = xp + (size_t)(4 * wb + 0) * K_IN;
        const float* xq1 = xp + (size_t)(4 * wb + 1) * K_IN;
        const float* xq2 = xp + (size_t)(4 * wb + 2) * K_IN;
        const float* xq3 = xp + (size_t)(4 * wb + 3) * K_IN;

#pragma unroll
        for (int c8 = 0; c8 < 8; ++c8) {
            const int c = ws * 8 + c8;   // 16B-chunk index within [0,32)
            const float4 wk = *reinterpret_cast<const float4*>(
                &buf[cur][ln * CHK + ((c ^ swz) << 2)]);
            const float4 x0 = *reinterpret_cast<const float4*>(xq0 + c8 * 4);
            const float4 x1 = *reinterpret_cast<const float4*>(xq1 + c8 * 4);
            const float4 x2 = *reinterpret_cast<const float4*>(xq2 + c8 * 4);
            const float4 x3 = *reinterpret_cast<const float4*>(xq3 + c8 * 4);

            {   const float p0 = x0.x * wk.x, p1 = x0.y * wk.y, p2 = x0.z * wk.z, p3 = x0.w * wk.w;
                mx0 = fmaxf(fmaxf(mx0, p0), p1); mx0 = fmaxf(fmaxf(mx0, p2), p3);
                mn0 = fminf(fminf(mn0, p0), p1); mn0 = fminf(fminf(mn0, p2), p3); }
            {   const float p0 = x1.x * wk.x, p1 = x1.y * wk.y, p2 = x1.z * wk.z, p3 = x1.w * wk.w;
                mx1 = fmaxf(fmaxf(mx1, p0), p1); mx1 = fmaxf(fmaxf(mx1, p2), p3);
                mn1 = fminf(fminf(mn1, p0), p1); mn1 = fminf(fminf(mn1, p2), p3); }
            {   const float p0 = x2.x * wk.x, p1 = x2.y * wk.y, p2 = x2.z * wk.z, p3 = x2.w * wk.w;
                mx2 = fmaxf(fmaxf(mx2, p0), p1); mx2 = fmaxf(fmaxf(mx2, p2), p3);
                mn2 = fminf(fminf(mn2, p0), p1); mn2 = fminf(fminf(mn2, p2), p3); }
            {   const float p0 = x3.x * wk.x, p1 = x3.y * wk.y, p2 = x3.z * wk.z, p3 = x3.w * wk.w;
                mx3 = fmaxf(fmaxf(mx3, p0), p1); mx3 = fmaxf(fmaxf(mx3, p2), p3);
                mn3 = fminf(fminf(mn3, p0), p1); mn3 = fminf(fminf(mn3, p2), p3); }
        }

        // write next chunk into the other buffer (safe: all waves left that
        // buffer's compute at the barrier above; current readers use buf[cur])
        if (cc + 1 < NCHK) {
#pragma unroll
            for (int i = 0; i < 4; ++i) {
                const int r = sr + 16 * i;
                *reinterpret_cast<float4*>(
                    &buf[cur ^ 1][r * CHK + ((sc ^ (r & 7)) << 2)]) = st[i];
            }
        }
    }

    // ---- 4-way k-sub reduce via LDS (aliases buf[0]; last compute read buf[1]) ----
    float* red = &buf[0][0];   // [wid][ln] float4: mx @0, mn @2048 floats (16 KB)
    *reinterpret_cast<float4*>(&red[(wid * 64 + ln) * 4]) =
        make_float4(mx0, mx1, mx2, mx3);
    *reinterpret_cast<float4*>(&red[2048 + (wid * 64 + ln) * 4]) =
        make_float4(mn0, mn1, mn2, mn3);
    __syncthreads();

    // 512 threads -> 512 outputs: row i = tid>>6 (0..7), col n = tid&63
    const int oi  = tid >> 6;
    const int on  = tid & 63;
    const int owb = oi >> 2;    // which b-half
    const int oii = oi & 3;     // row within quad = float4 element
    float MX = -FLT_MAX, MN = FLT_MAX;
#pragma unroll
    for (int s = 0; s < 4; ++s) {
        const int widx = s * 2 + owb;
        MX = fmaxf(MX, red[(widx * 64 + on) * 4 + oii]);
        MN = fminf(MN, red[2048 + (widx * 64 + on) * 4 + oii]);
    }
    out[(size_t)(b0 + oi) * N_OUT + n0 + on] = MX + MN + bias[n0 + on];
}

extern "C" void kernel_launch(void* const* d_in, const int* in_sizes, int n_in,
                              void* d_out, int out_size, void* d_ws, size_t ws_size,
                              hipStream_t stream) {
    const float* x    = (const float*)d_in[0];   // [256,1024]
    const float* w    = (const float*)d_in[1];   // [512,1024]
    const float* bias = (const float*)d_in[2];   // [512]
    float* out = (float*)d_out;                  // [256,512] f32
    (void)d_ws; (void)ws_size;

    mam_single<<<dim3(B_TOK / BT, N_OUT / NT), 512, 0, stream>>>(x, w, bias, out);
}